// Round 11
// baseline (732.889 us; speedup 1.0000x reference)
//
#include <hip/hip_runtime.h>
#include <cmath>

// PhaseAwareClassifier on MI355X — R11 (= R10 with exp2 intrinsic fix).
// R9 post-mortem: LDS read pipe dominant (480 b128/CU-step ~ 173us) + ~100us
// epilogue VALU. R10/11: 640-thread block (10 waves) covers N=128 cols; wave
// = 2 M-tiles x 4 N-tiles (Mg=5 x Ng=2). Cr A-frags persist in VGPRs (loaded
// once from global); Ci read from LDS. Per-wave LDS reads 60->50 per step for
// 2x columns. Dead rows 144..159 skipped (mg=4 waves own tile 8 only).
// Epilogue: rsq + exp2 (gsp2 pre-folds -2*log2(e)). Math = R8/R9 (7.8e-3).

#define NSTEPS  10
#define INJ_ST  4

typedef __bf16 bf16x8 __attribute__((ext_vector_type(8)));
typedef __bf16 bf16x4 __attribute__((ext_vector_type(4)));
typedef short  short8 __attribute__((ext_vector_type(8)));
typedef float  f32x4  __attribute__((ext_vector_type(4)));

// workspace layout (float offsets)
#define WS_MAX    0          // 1      enc_max (uint-ordered float)
#define WS_ENERGY 64         // 1280   energy[b][10]
#define WS_GSP    2048       // 160    gsp2[j] = -2*log2(e)*softplus(gain)
#define WS_GSP1   2304       // 160    gsp[j]  = softplus(gain)
#define WS_CONN   4096       // 2 bf16 matrices [20][160][8] chunked: Cr, Ci
#define WS_INJ    32768      // 100352 inj[b][49][16] = px * 1.02/enc_max

__global__ void k_init(float* ws) {
    int i = blockIdx.x * 256 + threadIdx.x;
    if (i == 0) ws[WS_MAX] = 0.f;
    if (i < 1280) ws[WS_ENERGY + i] = 0.f;
}

__global__ void k_max(const float* __restrict__ img, float* ws, int n) {
    __shared__ float sm[256];
    float v = 0.f;
    for (int i = blockIdx.x * blockDim.x + threadIdx.x; i < n; i += gridDim.x * blockDim.x)
        v = fmaxf(v, fabsf(img[i]));
    sm[threadIdx.x] = v;
    __syncthreads();
    for (int s = 128; s > 0; s >>= 1) {
        if (threadIdx.x < s) sm[threadIdx.x] = fmaxf(sm[threadIdx.x], sm[threadIdx.x + s]);
        __syncthreads();
    }
    if (threadIdx.x == 0)
        atomicMax((unsigned int*)(ws + WS_MAX), __float_as_uint(sm[0]));
}

__global__ void k_prep(const float* __restrict__ img,
                       const float* __restrict__ cr, const float* __restrict__ ci,
                       const float* __restrict__ phase, const float* __restrict__ gain,
                       float* ws) {
    int i = blockIdx.x * 256 + threadIdx.x;
    __bf16* Cb = (__bf16*)(ws + WS_CONN);
    if (i < 25600) {                       // (m=j row, k=s col) of A
        int m = i / 160, k = i % 160;
        float vr = 0.f, vi = 0.f;
        if (m < 131 && k < 131) {
            float a = cr[k * 131 + m], b = ci[k * 131 + m];
            float ph = phase[m];
            float cp = cosf(ph), sp = sinf(ph);
            vr = a * cp - b * sp;
            vi = a * sp + b * cp;
        }
        int ca = ((k >> 3) * 160 + m) * 8 + (k & 7);   // chunked addr
        Cb[ca]         = (__bf16)vr;
        Cb[25600 + ca] = (__bf16)vi;
    } else if (i < 25760) {
        int j = i - 25600;
        float g = 0.f;
        if (j < 131) {
            float x = gain[j];
            g = (x > 20.f) ? x : log1pf(expf(x));  // softplus
        }
        ws[WS_GSP + j]  = g * -2.8853901817f;       // -2*log2(e)*g
        ws[WS_GSP1 + j] = g;
    } else if (i < 25760 + 128 * 49 * 16) {
        int q = i - 25760;
        int m = q & 15, jj = (q >> 4) % 49, b = q / (49 * 16);
        int u = m >> 2, v2 = m & 3, pi = jj / 7, pj = jj % 7;
        float px = img[b * 784 + (pi * 4 + u) * 28 + (pj * 4 + v2)];
        float mx = ws[WS_MAX];
        float sc = (mx > 1e-8f) ? (1.02f / mx) : 1.02f;   // 0.85*4*0.3
        ws[WS_INJ + q] = px * sc;
    }
}

static __device__ __forceinline__ f32x4 MF(bf16x8 a, bf16x8 b, f32x4 c) {
    return __builtin_amdgcn_mfma_f32_16x16x32_bf16(a, b, c, 0, 0, 0);
}
static __device__ __forceinline__ bf16x8 bneg(bf16x8 a) {
    short8 t = __builtin_bit_cast(short8, a) ^ (short8)(short)0x8000;
    return __builtin_bit_cast(bf16x8, t);
}

__global__ __launch_bounds__(640, 1)
void k_main(const float* __restrict__ ws, float* __restrict__ energy) {
    __shared__ __bf16 OB[2][20 * 128 * 8];         // 81,920 B: Or, Oi chunked
    __shared__ __bf16 CiL[20 * 160 * 8];           // 51,200 B: Ci chunked
    __shared__ float scrE[10 * 128];               //  5,120 B  -> 138,240 total
    const int tid  = threadIdx.x;
    const int lane = tid & 63;
    const int ln15 = lane & 15;
    const int quad = lane >> 4;
    const int wv   = __builtin_amdgcn_readfirstlane(tid >> 6);  // 0..9
    const int mg   = wv >> 1;                       // 0..4 (M-group: tiles 2mg,2mg+1)
    const int ng   = wv & 1;                        // N-group: tiles 4ng..4ng+3
    const int npos = (mg == 4) ? 4 : 8;             // tile 9 (rows 144+) is dead
    const int nm   = (mg == 4) ? 1 : 2;
    const int b    = blockIdx.x >> 3;               // 8 blocks per image
    const int m    = ln15;

    const __bf16* __restrict__ Crg = (const __bf16*)(ws + WS_CONN);
    const __bf16* __restrict__ Cig = Crg + 25600;
    const float* __restrict__ gsp2 = ws + WS_GSP;
    const float* __restrict__ injb = ws + WS_INJ;

    __bf16* __restrict__ OBr = &OB[0][0];
    __bf16* __restrict__ OBi = &OB[1][0];

    // per-ntile encoding weight
    float wls[4];
#pragma unroll
    for (int q = 0; q < 4; ++q) {
        int l = (blockIdx.x * 8 + 4 * ng + q) & 63;
        wls[q] = 1.0f - fabsf((float)l - 32.0f) * (1.0f / 64.0f);
    }

    // ---- persistent A (Cr) fragments: 2 M-tiles x 5 kt, from global, once --
    bf16x8 acr[2][5];
#pragma unroll
    for (int m2 = 0; m2 < 2; ++m2)
#pragma unroll
        for (int kt = 0; kt < 5; ++kt)
            acr[m2][kt] = *(const bf16x8*)(Crg +
                (((kt * 4 + quad) * 160) + (2 * mg + m2) * 16 + ln15) * 8);

    // stage Ci -> LDS; zero O-state
    {
        const int4* src = (const int4*)Cig;
        int4* dst = (int4*)CiL;
        for (int i = tid; i < 3200; i += 640) dst[i] = src[i];
        int4* ob = (int4*)&OB[0][0];
        int4 z = {0, 0, 0, 0};
        for (int i = tid; i < 5120; i += 640) ob[i] = z;
    }

    f32x4 accr[8], acci[8];                         // acc == 4 * field
#pragma unroll
    for (int p = 0; p < 8; ++p) { accr[p] = (f32x4)0.f; acci[p] = (f32x4)0.f; }

    // injection (rows j<49 only -> waves mg 0,1)
    auto inj_add = [&]() {
        if (mg < 2) {
#pragma unroll
            for (int p = 0; p < 8; ++p) {
                const int j0 = (2 * mg + (p >> 2)) * 16 + quad * 4;
#pragma unroll
                for (int r = 0; r < 4; ++r) {
                    int j = j0 + r;
                    if (j < 49) accr[p][r] += injb[(b * 49 + j) * 16 + m] * wls[p & 3];
                }
            }
        }
    };

    // epilogue: out = tanh-rescale(0.25*acc) -> bf16 chunked LDS write
    auto epilogue = [&](bool last) {
        for (int p = 0; p < npos; ++p) {
            const int j0 = (2 * mg + (p >> 2)) * 16 + quad * 4;
            const int n  = (4 * ng + (p & 3)) * 16 + ln15;
            float g2[4];
            *(float4*)g2 = *(const float4*)(gsp2 + j0);
            bf16x4 pr, pi;
#pragma unroll
            for (int r = 0; r < 4; ++r) {
                float fr = accr[p][r] * 0.25f;
                float fi = acci[p][r] * 0.25f;
                float mag2 = fmaf(fr, fr, fmaf(fi, fi, 1e-8f));
                float rmag = __builtin_amdgcn_rsqf(mag2);      // 1/mag
                float magv = mag2 * rmag;                      // mag
                float e = __builtin_amdgcn_exp2f(g2[r] * magv); // exp(-2*g*mag)
                float th = 1.0f - 2.0f * e * __builtin_amdgcn_rcpf(1.0f + e);
                float scv = th * rmag;                         // tanh/mag
                float orv = fr * scv, oiv = fi * scv;
                pr[r] = (__bf16)orv; pi[r] = (__bf16)oiv;
                if (last) {
                    int j = j0 + r;
                    if (j >= 121 && j <= 130)
                        scrE[(j - 121) * 128 + n] = orv * orv + oiv * oiv;
                }
            }
            const int off = ((j0 >> 3) * 128 + n) * 8 + (j0 & 7);
            *(bf16x4*)(OBr + off) = pr;
            *(bf16x4*)(OBi + off) = pi;
        }
    };

    __syncthreads();
    inj_add();                                      // t = 0 (out is zero)
    epilogue(false);
    __syncthreads();

    for (int t = 1; t < NSTEPS; ++t) {
#pragma unroll
        for (int p = 0; p < 8; ++p) { accr[p] *= 0.85f; acci[p] *= 0.85f; }
        if (t < INJ_ST) inj_add();

        // ---- MFMA: G += C * O (complex bf16; Cr in regs, Ci/O from LDS) ---
#pragma unroll
        for (int kt = 0; kt < 5; ++kt) {
            const int kch = kt * 4 + quad;
            bf16x8 ai[2];
#pragma unroll
            for (int m2 = 0; m2 < 2; ++m2)
                if (m2 < nm)
                    ai[m2] = *(const bf16x8*)(CiL +
                        ((kch * 160) + (2 * mg + m2) * 16 + ln15) * 8);
#pragma unroll
            for (int n4 = 0; n4 < 4; ++n4) {
                const int boff = (kch * 128 + (4 * ng + n4) * 16 + ln15) * 8;
                bf16x8 b_r  = *(const bf16x8*)(OBr + boff);
                bf16x8 b_i  = *(const bf16x8*)(OBi + boff);
                bf16x8 b_ni = bneg(b_i);
#pragma unroll
                for (int m2 = 0; m2 < 2; ++m2) {
                    if (m2 < nm) {
                        const int p = m2 * 4 + n4;
                        f32x4 ar = accr[p], aiv = acci[p];
                        ar  = MF(acr[m2][kt], b_r,  ar);    // G_r += Cr*Or
                        ar  = MF(ai[m2],      b_ni, ar);    // G_r -= Ci*Oi
                        aiv = MF(acr[m2][kt], b_i,  aiv);   // G_i += Cr*Oi
                        aiv = MF(ai[m2],      b_r,  aiv);   // G_i += Ci*Or
                        accr[p] = ar; acci[p] = aiv;
                    }
                }
            }
        }
        __syncthreads();   // all reads of OB done
        epilogue(t == NSTEPS - 1);
        __syncthreads();   // OB ready for next step
    }

    // ---- energy: scrE[10][128] holds exact fp32 |out|^2 ----
    if (tid < 10) {
        float ssum = 0.f;
        for (int cc = 0; cc < 128; ++cc) ssum += scrE[tid * 128 + cc];
        atomicAdd(energy + b * 10 + tid, ssum);
    }
}

__global__ void k_readout(const float* __restrict__ ws,
                          const float* __restrict__ W,
                          const float* __restrict__ bias,
                          float* __restrict__ out) {
    int i = blockIdx.x * 256 + threadIdx.x;
    if (i < 1280) {
        int b = i / 10, o = i % 10;
        float s = bias[o];
#pragma unroll
        for (int f = 0; f < 10; ++f) {
            float feat = log1pf(ws[WS_ENERGY + b * 10 + f] + 1e-8f);
            s = fmaf(feat, W[o * 10 + f], s);
        }
        out[i] = s;
    }
}

extern "C" void kernel_launch(void* const* d_in, const int* in_sizes, int n_in,
                              void* d_out, int out_size, void* d_ws, size_t ws_size,
                              hipStream_t stream) {
    const float* images = (const float*)d_in[0];
    const float* conn_r = (const float*)d_in[1];
    const float* conn_i = (const float*)d_in[2];
    const float* phase  = (const float*)d_in[3];
    const float* gain   = (const float*)d_in[4];
    const float* W      = (const float*)d_in[5];
    const float* bias   = (const float*)d_in[6];
    float* ws  = (float*)d_ws;
    float* out = (float*)d_out;

    hipLaunchKernelGGL(k_init, dim3(6), dim3(256), 0, stream, ws);
    hipLaunchKernelGGL(k_max, dim3(98), dim3(256), 0, stream, images, ws, 128 * 28 * 28);
    hipLaunchKernelGGL(k_prep, dim3(493), dim3(256), 0, stream,
                       images, conn_r, conn_i, phase, gain, ws);
    hipLaunchKernelGGL(k_main, dim3(1024), dim3(640), 0, stream, ws, ws + WS_ENERGY);
    hipLaunchKernelGGL(k_readout, dim3(5), dim3(256), 0, stream, ws, W, bias, out);
}

// Round 12
// 424.792 us; speedup vs baseline: 1.7253x; 1.7253x over previous
//
#include <hip/hip_runtime.h>
#include <cmath>

// PhaseAwareClassifier on MI355X — R12: R11 with ALL loop bounds constant.
// R11 post-mortem: runtime npos/nm bounds -> acc arrays dynamically indexed
// -> SROA fails -> accumulators in scratch (690MB WRITE_SIZE, VGPR=84).
// R12: every wave does the full 2 M-tiles x 4 N-tiles (tile 9 = rows 144+
// computes zeros harmlessly; 10% extra MFMA << scratch cost). kt fully
// unrolled so acr[m2][kt] indices are constants. Cr persists in VGPRs,
// Ci + O in LDS. Epilogue rsq+exp2. Math = R8/R9/R11 (absmax 7.8e-3).

#define NSTEPS  10
#define INJ_ST  4

typedef __bf16 bf16x8 __attribute__((ext_vector_type(8)));
typedef __bf16 bf16x4 __attribute__((ext_vector_type(4)));
typedef short  short8 __attribute__((ext_vector_type(8)));
typedef float  f32x4  __attribute__((ext_vector_type(4)));

// workspace layout (float offsets)
#define WS_MAX    0          // 1      enc_max (uint-ordered float)
#define WS_ENERGY 64         // 1280   energy[b][10]
#define WS_GSP    2048       // 160    gsp2[j] = -2*log2(e)*softplus(gain)
#define WS_CONN   4096       // 2 bf16 matrices [20][160][8] chunked: Cr, Ci
#define WS_INJ    32768      // 100352 inj[b][49][16] = px * 1.02/enc_max

__global__ void k_init(float* ws) {
    int i = blockIdx.x * 256 + threadIdx.x;
    if (i == 0) ws[WS_MAX] = 0.f;
    if (i < 1280) ws[WS_ENERGY + i] = 0.f;
}

__global__ void k_max(const float* __restrict__ img, float* ws, int n) {
    __shared__ float sm[256];
    float v = 0.f;
    for (int i = blockIdx.x * blockDim.x + threadIdx.x; i < n; i += gridDim.x * blockDim.x)
        v = fmaxf(v, fabsf(img[i]));
    sm[threadIdx.x] = v;
    __syncthreads();
    for (int s = 128; s > 0; s >>= 1) {
        if (threadIdx.x < s) sm[threadIdx.x] = fmaxf(sm[threadIdx.x], sm[threadIdx.x + s]);
        __syncthreads();
    }
    if (threadIdx.x == 0)
        atomicMax((unsigned int*)(ws + WS_MAX), __float_as_uint(sm[0]));
}

__global__ void k_prep(const float* __restrict__ img,
                       const float* __restrict__ cr, const float* __restrict__ ci,
                       const float* __restrict__ phase, const float* __restrict__ gain,
                       float* ws) {
    int i = blockIdx.x * 256 + threadIdx.x;
    __bf16* Cb = (__bf16*)(ws + WS_CONN);
    if (i < 25600) {                       // (m=j row, k=s col) of A
        int m = i / 160, k = i % 160;
        float vr = 0.f, vi = 0.f;
        if (m < 131 && k < 131) {
            float a = cr[k * 131 + m], b = ci[k * 131 + m];
            float ph = phase[m];
            float cp = cosf(ph), sp = sinf(ph);
            vr = a * cp - b * sp;
            vi = a * sp + b * cp;
        }
        int ca = ((k >> 3) * 160 + m) * 8 + (k & 7);   // chunked addr
        Cb[ca]         = (__bf16)vr;
        Cb[25600 + ca] = (__bf16)vi;
    } else if (i < 25760) {
        int j = i - 25600;
        float g = 0.f;
        if (j < 131) {
            float x = gain[j];
            g = (x > 20.f) ? x : log1pf(expf(x));  // softplus
        }
        ws[WS_GSP + j] = g * -2.8853901817f;        // -2*log2(e)*g
    } else if (i < 25760 + 128 * 49 * 16) {
        int q = i - 25760;
        int m = q & 15, jj = (q >> 4) % 49, b = q / (49 * 16);
        int u = m >> 2, v2 = m & 3, pi = jj / 7, pj = jj % 7;
        float px = img[b * 784 + (pi * 4 + u) * 28 + (pj * 4 + v2)];
        float mx = ws[WS_MAX];
        float sc = (mx > 1e-8f) ? (1.02f / mx) : 1.02f;   // 0.85*4*0.3
        ws[WS_INJ + q] = px * sc;
    }
}

static __device__ __forceinline__ f32x4 MF(bf16x8 a, bf16x8 b, f32x4 c) {
    return __builtin_amdgcn_mfma_f32_16x16x32_bf16(a, b, c, 0, 0, 0);
}
static __device__ __forceinline__ bf16x8 bneg(bf16x8 a) {
    short8 t = __builtin_bit_cast(short8, a) ^ (short8)(short)0x8000;
    return __builtin_bit_cast(bf16x8, t);
}

__global__ __launch_bounds__(640, 1)
void k_main(const float* __restrict__ ws, float* __restrict__ energy) {
    __shared__ __bf16 OB[2][20 * 128 * 8];         // 81,920 B: Or, Oi chunked
    __shared__ __bf16 CiL[20 * 160 * 8];           // 51,200 B: Ci chunked
    __shared__ float scrE[10 * 128];               //  5,120 B  -> 138,240 total
    const int tid  = threadIdx.x;
    const int lane = tid & 63;
    const int ln15 = lane & 15;
    const int quad = lane >> 4;
    const int wv   = __builtin_amdgcn_readfirstlane(tid >> 6);  // 0..9
    const int mg   = wv >> 1;                       // 0..4: M-tiles 2mg, 2mg+1
    const int ng   = wv & 1;                        // N-tiles 4ng..4ng+3
    const int b    = blockIdx.x >> 3;               // 8 blocks per image
    const int m    = ln15;

    const __bf16* __restrict__ Crg = (const __bf16*)(ws + WS_CONN);
    const __bf16* __restrict__ Cig = Crg + 25600;
    const float* __restrict__ gsp2 = ws + WS_GSP;
    const float* __restrict__ injb = ws + WS_INJ;

    __bf16* __restrict__ OBr = &OB[0][0];
    __bf16* __restrict__ OBi = &OB[1][0];

    // per-ntile encoding weight
    float wls[4];
#pragma unroll
    for (int q = 0; q < 4; ++q) {
        int l = (blockIdx.x * 8 + 4 * ng + q) & 63;
        wls[q] = 1.0f - fabsf((float)l - 32.0f) * (1.0f / 64.0f);
    }

    // ---- persistent A (Cr) fragments: 2 M-tiles x 5 kt, from global, once --
    bf16x8 acr[2][5];
#pragma unroll
    for (int m2 = 0; m2 < 2; ++m2)
#pragma unroll
        for (int kt = 0; kt < 5; ++kt)
            acr[m2][kt] = *(const bf16x8*)(Crg +
                (((kt * 4 + quad) * 160) + (2 * mg + m2) * 16 + ln15) * 8);

    // stage Ci -> LDS; zero O-state
    {
        const int4* src = (const int4*)Cig;
        int4* dst = (int4*)CiL;
        for (int i = tid; i < 3200; i += 640) dst[i] = src[i];
        int4* ob = (int4*)&OB[0][0];
        int4 z = {0, 0, 0, 0};
        for (int i = tid; i < 5120; i += 640) ob[i] = z;
    }

    f32x4 accr[8], acci[8];                         // acc == 4 * field
#pragma unroll
    for (int p = 0; p < 8; ++p) { accr[p] = (f32x4)0.f; acci[p] = (f32x4)0.f; }

    // injection (rows j<49 -> only waves with mg<2 have any; j<49 predicate
    // is per-element cndmask, indices all constant)
    auto inj_add = [&]() {
        if (mg < 2) {
#pragma unroll
            for (int p = 0; p < 8; ++p) {
                const int j0 = (2 * mg + (p >> 2)) * 16 + quad * 4;
#pragma unroll
                for (int r = 0; r < 4; ++r) {
                    int j = j0 + r;
                    if (j < 49) accr[p][r] += injb[(b * 49 + j) * 16 + m] * wls[p & 3];
                }
            }
        }
    };

    // epilogue: out = tanh-rescale(0.25*acc) -> bf16 chunked LDS write
    auto epilogue = [&](bool last) {
#pragma unroll
        for (int p = 0; p < 8; ++p) {
            const int j0 = (2 * mg + (p >> 2)) * 16 + quad * 4;
            const int n  = (4 * ng + (p & 3)) * 16 + ln15;
            float g2[4];
            *(float4*)g2 = *(const float4*)(gsp2 + j0);
            bf16x4 pr, pi;
#pragma unroll
            for (int r = 0; r < 4; ++r) {
                float fr = accr[p][r] * 0.25f;
                float fi = acci[p][r] * 0.25f;
                float mag2 = fmaf(fr, fr, fmaf(fi, fi, 1e-8f));
                float rmag = __builtin_amdgcn_rsqf(mag2);       // 1/mag
                float magv = mag2 * rmag;                       // mag
                float e = __builtin_amdgcn_exp2f(g2[r] * magv); // exp(-2*g*mag)
                float th = 1.0f - 2.0f * e * __builtin_amdgcn_rcpf(1.0f + e);
                float scv = th * rmag;                          // tanh/mag
                float orv = fr * scv, oiv = fi * scv;
                pr[r] = (__bf16)orv; pi[r] = (__bf16)oiv;
                if (last) {
                    int j = j0 + r;
                    if (j >= 121 && j <= 130)
                        scrE[(j - 121) * 128 + n] = orv * orv + oiv * oiv;
                }
            }
            const int off = ((j0 >> 3) * 128 + n) * 8 + (j0 & 7);
            *(bf16x4*)(OBr + off) = pr;
            *(bf16x4*)(OBi + off) = pi;
        }
    };

    __syncthreads();
    inj_add();                                      // t = 0 (out is zero)
    epilogue(false);
    __syncthreads();

    for (int t = 1; t < NSTEPS; ++t) {
#pragma unroll
        for (int p = 0; p < 8; ++p) { accr[p] *= 0.85f; acci[p] *= 0.85f; }
        if (t < INJ_ST) inj_add();

        // ---- MFMA: G += C * O (complex bf16; Cr in regs, Ci/O from LDS) ---
#pragma unroll
        for (int kt = 0; kt < 5; ++kt) {
            const int kch = kt * 4 + quad;
            bf16x8 ai[2];
#pragma unroll
            for (int m2 = 0; m2 < 2; ++m2)
                ai[m2] = *(const bf16x8*)(CiL +
                    ((kch * 160) + (2 * mg + m2) * 16 + ln15) * 8);
#pragma unroll
            for (int n4 = 0; n4 < 4; ++n4) {
                const int boff = (kch * 128 + (4 * ng + n4) * 16 + ln15) * 8;
                bf16x8 b_r  = *(const bf16x8*)(OBr + boff);
                bf16x8 b_i  = *(const bf16x8*)(OBi + boff);
                bf16x8 b_ni = bneg(b_i);
#pragma unroll
                for (int m2 = 0; m2 < 2; ++m2) {
                    const int p = m2 * 4 + n4;
                    f32x4 ar = accr[p], aiv = acci[p];
                    ar  = MF(acr[m2][kt], b_r,  ar);    // G_r += Cr*Or
                    ar  = MF(ai[m2],      b_ni, ar);    // G_r -= Ci*Oi
                    aiv = MF(acr[m2][kt], b_i,  aiv);   // G_i += Cr*Oi
                    aiv = MF(ai[m2],      b_r,  aiv);   // G_i += Ci*Or
                    accr[p] = ar; acci[p] = aiv;
                }
            }
        }
        __syncthreads();   // all reads of OB done
        epilogue(t == NSTEPS - 1);
        __syncthreads();   // OB ready for next step
    }

    // ---- energy: scrE[10][128] holds exact fp32 |out|^2 ----
    if (tid < 10) {
        float ssum = 0.f;
        for (int cc = 0; cc < 128; ++cc) ssum += scrE[tid * 128 + cc];
        atomicAdd(energy + b * 10 + tid, ssum);
    }
}

__global__ void k_readout(const float* __restrict__ ws,
                          const float* __restrict__ W,
                          const float* __restrict__ bias,
                          float* __restrict__ out) {
    int i = blockIdx.x * 256 + threadIdx.x;
    if (i < 1280) {
        int b = i / 10, o = i % 10;
        float s = bias[o];
#pragma unroll
        for (int f = 0; f < 10; ++f) {
            float feat = log1pf(ws[WS_ENERGY + b * 10 + f] + 1e-8f);
            s = fmaf(feat, W[o * 10 + f], s);
        }
        out[i] = s;
    }
}

extern "C" void kernel_launch(void* const* d_in, const int* in_sizes, int n_in,
                              void* d_out, int out_size, void* d_ws, size_t ws_size,
                              hipStream_t stream) {
    const float* images = (const float*)d_in[0];
    const float* conn_r = (const float*)d_in[1];
    const float* conn_i = (const float*)d_in[2];
    const float* phase  = (const float*)d_in[3];
    const float* gain   = (const float*)d_in[4];
    const float* W      = (const float*)d_in[5];
    const float* bias   = (const float*)d_in[6];
    float* ws  = (float*)d_ws;
    float* out = (float*)d_out;

    hipLaunchKernelGGL(k_init, dim3(6), dim3(256), 0, stream, ws);
    hipLaunchKernelGGL(k_max, dim3(98), dim3(256), 0, stream, images, ws, 128 * 28 * 28);
    hipLaunchKernelGGL(k_prep, dim3(493), dim3(256), 0, stream,
                       images, conn_r, conn_i, phase, gain, ws);
    hipLaunchKernelGGL(k_main, dim3(1024), dim3(640), 0, stream, ws, ws + WS_ENERGY);
    hipLaunchKernelGGL(k_readout, dim3(5), dim3(256), 0, stream, ws, W, bias, out);
}